// Round 8
// baseline (102.599 us; speedup 1.0000x reference)
//
#include <hip/hip_runtime.h>

#define BATCH  65536
#define NIN    9
#define NHID   100
#define TSTEPS 25
#define GSZ    4              // lanes cooperating on one batch element
#define HPT    (NHID / GSZ)   // 25 hidden neurons per lane

typedef float v2f __attribute__((ext_vector_type(2)));

// f64 m-chain (spike decisions track the f64 numpy arbiter) + packed f32
// fc2 accumulators. Round-8 changes:
//  - NO min-waves launch bound: with (256,4) the allocator split state as
//    60 VGPR + ~64 AGPR and (theory) bracketed every acc update with
//    v_accvgpr moves (~2500 cyc/wave). Unbounded, acc lives in arch VGPRs.
//  - FOUR interleaved neuron chains: ~56 issue-cyc between dependent f64
//    ops >> ~24-cyc chain latency -> latency-tolerant at 2 waves/SIMD.
//  - fc2 add order remains ascending j -> bit-identical to rounds 5/7.
__global__ __launch_bounds__(256) void snn_kernel(
    const float* __restrict__ x,  const float* __restrict__ W1,
    const float* __restrict__ b1, const float* __restrict__ W2,
    const float* __restrict__ b2, float* __restrict__ out)
{
    __shared__ double sW1[NHID * NIN];   // [h][i], promoted to f64
    __shared__ double sb1[NHID];
    __shared__ float  sW2[2 * NHID];     // [o][h], f32
    __shared__ double sb2[2];

    int tid = threadIdx.x;
    for (int i = tid; i < NHID * NIN; i += 256) sW1[i] = (double)W1[i];
    if (tid < NHID)     sb1[tid] = (double)b1[tid];
    if (tid < 2 * NHID) sW2[tid] = W2[tid];
    if (tid < 2)        sb2[tid] = (double)b2[tid];
    __syncthreads();

    int gtid = blockIdx.x * 256 + tid;
    int b  = gtid >> 2;     // batch element
    int hp = gtid & 3;      // neuron-quarter owned by this lane

    // x row in f32; widened at use (one cvt feeds 4 chains' FMAs).
    float xv[NIN];
    const float* xp = x + b * NIN;
#pragma unroll
    for (int i = 0; i < NIN; ++i) xv[i] = xp[i];

    // per-step fc2 partial sums: packed f32 pair (50 VGPRs, arch file)
    v2f acc[TSTEPS];
#pragma unroll
    for (int t = 0; t < TSTEPS; ++t) acc[t] = (v2f){0.f, 0.f};

    int h0 = hp * HPT;

    // 6 quads of neurons, 4 chains interleaved for ILP
#pragma unroll 1
    for (int j = 0; j < HPT - 1; j += 4) {
        const double* wrA = &sW1[(h0 + j)     * NIN];
        const double* wrB = &sW1[(h0 + j + 1) * NIN];
        const double* wrC = &sW1[(h0 + j + 2) * NIN];
        const double* wrD = &sW1[(h0 + j + 3) * NIN];
        double cA = 0.0, cB = 0.0, cC = 0.0, cD = 0.0;
#pragma unroll
        for (int i = 0; i < NIN; ++i) {
            double xd = (double)xv[i];
            cA += wrA[i] * xd;
            cB += wrB[i] * xd;
            cC += wrC[i] * xd;
            cD += wrD[i] * xd;
        }
        cA += sb1[h0 + j];     cB += sb1[h0 + j + 1];
        cC += sb1[h0 + j + 2]; cD += sb1[h0 + j + 3];
        double cA1 = cA - 1.0, cB1 = cB - 1.0, cC1 = cC - 1.0, cD1 = cD - 1.0;
        v2f wA = (v2f){sW2[h0 + j],     sW2[NHID + h0 + j]};
        v2f wB = (v2f){sW2[h0 + j + 1], sW2[NHID + h0 + j + 1]};
        v2f wC = (v2f){sW2[h0 + j + 2], sW2[NHID + h0 + j + 2]};
        v2f wD = (v2f){sW2[h0 + j + 3], sW2[NHID + h0 + j + 3]};

        double mA = 0.0, mB = 0.0, mC = 0.0, mD = 0.0;
        bool sA = false, sB = false, sC = false, sD = false;
#pragma unroll
        for (int t = 0; t < TSTEPS; ++t) {
            mA = 0.95 * mA + (sA ? cA1 : cA);
            mB = 0.95 * mB + (sB ? cB1 : cB);
            mC = 0.95 * mC + (sC ? cC1 : cC);
            mD = 0.95 * mD + (sD ? cD1 : cD);
            sA = (mA > 1.0);  sB = (mB > 1.0);
            sC = (mC > 1.0);  sD = (mD > 1.0);
            float dA = sA ? 1.f : 0.f;
            float dB = sB ? 1.f : 0.f;
            float dC = sC ? 1.f : 0.f;
            float dD = sD ? 1.f : 0.f;
            acc[t] += (v2f){dA, dA} * wA;   // ascending j order preserved:
            acc[t] += (v2f){dB, dB} * wB;   // j, j+1, j+2, j+3
            acc[t] += (v2f){dC, dC} * wC;
            acc[t] += (v2f){dD, dD} * wD;
        }
    }

    // tail neuron (j = 24)
    {
        int h = h0 + HPT - 1;
        const double* wr = &sW1[h * NIN];
        double c = 0.0;
#pragma unroll
        for (int i = 0; i < NIN; ++i) c += wr[i] * (double)xv[i];
        c += sb1[h];
        double c1 = c - 1.0;
        v2f w = (v2f){sW2[h], sW2[NHID + h]};
        double m = 0.0;
        bool s = false;
#pragma unroll
        for (int t = 0; t < TSTEPS; ++t) {
            m = 0.95 * m + (s ? c1 : c);
            s = (m > 1.0);
            float d = s ? 1.f : 0.f;
            acc[t] += (v2f){d, d} * w;
        }
    }

    // reduce the 4 partial fc2 sums per quad (width-4 butterfly, f32)
#pragma unroll
    for (int t = 0; t < TSTEPS; ++t) {
        float v0 = acc[t][0], v1 = acc[t][1];
        v0 += __shfl_xor(v0, 1);  v0 += __shfl_xor(v0, 2);
        v1 += __shfl_xor(v1, 1);  v1 += __shfl_xor(v1, 2);
        acc[t][0] = v0;  acc[t][1] = v1;
    }

    // mem2 recurrence in f64; lane hp==0 stores f32
    if (hp == 0) {
        double m20 = 0.0, m21 = 0.0;
        double bb0 = sb2[0], bb1 = sb2[1];
        float* op = out + (size_t)b * 2;
#pragma unroll
        for (int t = 0; t < TSTEPS; ++t) {
            double r0 = (m20 > 1.0) ? 1.0 : 0.0;
            double r1 = (m21 > 1.0) ? 1.0 : 0.0;
            m20 = 0.95 * m20 + ((double)acc[t][0] + bb0) - r0;
            m21 = 0.95 * m21 + ((double)acc[t][1] + bb1) - r1;
            *(float2*)(op + (size_t)t * (BATCH * 2)) =
                make_float2((float)m20, (float)m21);
        }
    }
}

extern "C" void kernel_launch(void* const* d_in, const int* in_sizes, int n_in,
                              void* d_out, int out_size, void* d_ws, size_t ws_size,
                              hipStream_t stream) {
    const float* x  = (const float*)d_in[0];
    const float* W1 = (const float*)d_in[1];
    const float* b1 = (const float*)d_in[2];
    const float* W2 = (const float*)d_in[3];
    const float* b2 = (const float*)d_in[4];
    float* out = (float*)d_out;

    dim3 grid((BATCH * GSZ) / 256), block(256);
    hipLaunchKernelGGL(snn_kernel, grid, block, 0, stream, x, W1, b1, W2, b2, out);
}